// Round 8
// baseline (327.129 us; speedup 1.0000x reference)
//
#include <hip/hip_runtime.h>
#include <math.h>
#include <float.h>

#define N 8192
#define D 64
#define NK 90               // neighbors kept (K+1=91 incl self; self excluded at select)
#define NK1 (NK + 1)        // histogram target including self
#define BMR 32              // rows per band
#define NBAND (N / BMR)     // 256
#define HCOL (N / 2)        // 4096 cols per half-block
#define NWAVE 16
#define BCOL (NWAVE * 32)   // 512 cols per step
#define NSTEP (HCOL / BCOL) // 8
#define NBIN 256
#define CAP 256             // global candidate buffer per row
#define QS 4                // CAP/64

typedef __attribute__((ext_vector_type(8))) short short8v;
typedef __attribute__((ext_vector_type(16))) float f32x16;

__device__ __forceinline__ unsigned short f2bf(float f) {
    unsigned u = __float_as_uint(f);
    unsigned r = (u + 0x7FFFu + ((u >> 16) & 1u)) >> 16;   // RNE
    return (unsigned short)r;
}
__device__ __forceinline__ float bf2f(unsigned short h) {
    return __uint_as_float(((unsigned)h) << 16);
}

// ------------- kernel A: split-bf16 convert + row norms + max + gcnt=0 ------
__global__ void k_prep(const float* __restrict__ x, unsigned short* __restrict__ xhi,
                       unsigned short* __restrict__ xlo, float* __restrict__ sq,
                       int* __restrict__ maxbits, int* __restrict__ gcnt) {
    const int r = blockIdx.x * 256 + threadIdx.x;
    const float4* p = (const float4*)(x + (size_t)r * D);
    ushort4* ph = (ushort4*)(xhi + (size_t)r * D);
    ushort4* pl = (ushort4*)(xlo + (size_t)r * D);
    float s = 0.f;
#pragma unroll
    for (int q = 0; q < D / 4; ++q) {
        float4 v = p[q];
        s += v.x * v.x + v.y * v.y + v.z * v.z + v.w * v.w;
        ushort4 hh, ll;
        hh.x = f2bf(v.x); ll.x = f2bf(v.x - bf2f(hh.x));
        hh.y = f2bf(v.y); ll.y = f2bf(v.y - bf2f(hh.y));
        hh.z = f2bf(v.z); ll.z = f2bf(v.z - bf2f(hh.z));
        hh.w = f2bf(v.w); ll.w = f2bf(v.w - bf2f(hh.w));
        ph[q] = hh; pl[q] = ll;
    }
    sq[r] = s;
    gcnt[r] = 0;
    // wave max then one atomic (positive floats: int-bit compare monotone;
    // poisoned 0xAAAAAAAA is negative as int, any positive wins)
    float m = s;
    for (int o = 32; o > 0; o >>= 1) m = fmaxf(m, __shfl_xor(m, o, 64));
    if ((threadIdx.x & 63) == 0) atomicMax(maxbits, __float_as_int(m));
}

// ---- shared MFMA dot core: MUST be bit-identical between hist & collect ----
__device__ __forceinline__ f32x16 dot_acc(const unsigned short* __restrict__ xhi,
                                          const unsigned short* __restrict__ xlo,
                                          const short8v* ahi, const short8v* alo,
                                          int gj, int h) {
    f32x16 acc;
#pragma unroll
    for (int i = 0; i < 16; ++i) acc[i] = 0.f;
    const unsigned short* bh = xhi + (size_t)gj * D + 8 * h;
    const unsigned short* bl = xlo + (size_t)gj * D + 8 * h;
#pragma unroll
    for (int ks = 0; ks < 4; ++ks) {
        short8v bhiv = *(const short8v*)(bh + ks * 16);
        short8v blov = *(const short8v*)(bl + ks * 16);
        acc = __builtin_amdgcn_mfma_f32_32x32x16_bf16(ahi[ks], bhiv, acc, 0, 0, 0);
        acc = __builtin_amdgcn_mfma_f32_32x32x16_bf16(ahi[ks], blov, acc, 0, 0, 0);
        acc = __builtin_amdgcn_mfma_f32_32x32x16_bf16(alo[ks], bhiv, acc, 0, 0, 0);
    }
    return acc;
}

// -------- kernel B: histogram sweep over a 32-row x 4096-col half ----------
__global__ __launch_bounds__(1024) void k_hist(const unsigned short* __restrict__ xhi,
                                               const unsigned short* __restrict__ xlo,
                                               const float* __restrict__ sq,
                                               const int* __restrict__ maxbits,
                                               unsigned short* __restrict__ ghist) {
    __shared__ int hist[BMR][NBIN];   // 32 KB -> 2 blocks/CU

    const int tid = threadIdx.x;
    const int lane = tid & 63;
    const int h = lane >> 5;
    const int wv = tid >> 6;
    const int band = blockIdx.x >> 1;
    const int colbase = (blockIdx.x & 1) * HCOL;
    const int row0 = band * BMR;

    for (int e = tid; e < BMR * NBIN; e += 1024) ((int*)hist)[e] = 0;

    const float hi = 4.0f * __int_as_float(maxbits[0]) + 1.0f;   // > any d2
    const float scale = (float)NBIN / hi;
    const float ns = -2.0f * scale;

    short8v ahi_[4], alo_[4];
    const size_t abase = (size_t)(row0 + (lane & 31)) * D + 8 * h;
#pragma unroll
    for (int ks = 0; ks < 4; ++ks) {
        ahi_[ks] = *(const short8v*)(xhi + abase + ks * 16);
        alo_[ks] = *(const short8v*)(xlo + abase + ks * 16);
    }
    float sia_s[4][4];
#pragma unroll
    for (int q = 0; q < 4; ++q) {
        float4 t = *(const float4*)(sq + row0 + 8 * q + 4 * h);
        sia_s[q][0] = t.x * scale; sia_s[q][1] = t.y * scale;
        sia_s[q][2] = t.z * scale; sia_s[q][3] = t.w * scale;
    }
    __syncthreads();

    for (int s = 0; s < NSTEP; ++s) {
        const int gj = colbase + s * BCOL + wv * 32 + (lane & 31);
        const float sjs = sq[gj] * scale;
        f32x16 acc = dot_acc(xhi, xlo, ahi_, alo_, gj, h);
#pragma unroll
        for (int q = 0; q < 4; ++q)
#pragma unroll
            for (int j = 0; j < 4; ++j) {
                const float binf = fmaf(ns, acc[4 * q + j], sia_s[q][j] + sjs);
                const int bin = (int)fminf(fmaxf(binf, 0.f), (float)(NBIN - 1));
                atomicAdd(&hist[8 * q + 4 * h + j][bin], 1);
            }
    }
    __syncthreads();

    unsigned short* gdst = ghist + (size_t)blockIdx.x * BMR * NBIN;
    for (int e = tid; e < BMR * NBIN; e += 1024) gdst[e] = (unsigned short)((const int*)hist)[e];
}

// -------- kernel C: B* extraction + collect sweep (identical arithmetic) ----
__global__ __launch_bounds__(1024) void k_collect(const unsigned short* __restrict__ xhi,
                                                  const unsigned short* __restrict__ xlo,
                                                  const float* __restrict__ sq,
                                                  const int* __restrict__ maxbits,
                                                  const unsigned short* __restrict__ ghist,
                                                  int* __restrict__ gcnt,
                                                  float* __restrict__ gbufv,
                                                  unsigned short* __restrict__ gbufi) {
    __shared__ float bsf[BMR];        // float(B* + 1)

    const int tid = threadIdx.x;
    const int lane = tid & 63;
    const int h = lane >> 5;
    const int wv = tid >> 6;
    const int band = blockIdx.x >> 1;
    const int colbase = (blockIdx.x & 1) * HCOL;
    const int row0 = band * BMR;

    const float hi = 4.0f * __int_as_float(maxbits[0]) + 1.0f;
    const float scale = (float)NBIN / hi;
    const float inv_scale = hi / (float)NBIN;
    const float ns = -2.0f * scale;

    // B* per row: wave handles 2 rows; lane covers 4 bins of each half's partial
#pragma unroll 1
    for (int rr = 0; rr < 2; ++rr) {
        const int r = wv * 2 + rr;
        const ushort4 h0 = *(const ushort4*)(ghist + ((size_t)(band * 2 + 0) * BMR + r) * NBIN + lane * 4);
        const ushort4 h1 = *(const ushort4*)(ghist + ((size_t)(band * 2 + 1) * BMR + r) * NBIN + lane * 4);
        int pc[4] = {h0.x + h1.x, h0.y + h1.y, h0.z + h1.z, h0.w + h1.w};
        const int ssum = pc[0] + pc[1] + pc[2] + pc[3];
        int incl = ssum;
        for (int o = 1; o < 64; o <<= 1) {
            int t = __shfl_up(incl, o, 64);
            if (lane >= o) incl += t;
        }
        const int excl = incl - ssum;
        const bool has = (excl < NK1) && (incl >= NK1);
        const unsigned long long m = __ballot(has);
        const int src = __ffsll((unsigned long long)m) - 1;
        int bsel = NBIN - 1;
        if (has) {
            int c = excl;
#pragma unroll
            for (int b = 0; b < 4; ++b) {
                c += pc[b];
                if (c >= NK1) { bsel = lane * 4 + b; break; }
            }
        }
        bsel = __shfl(bsel, src, 64);
        if (lane == 0) bsf[r] = (float)(bsel + 1);
    }

    short8v ahi_[4], alo_[4];
    const size_t abase = (size_t)(row0 + (lane & 31)) * D + 8 * h;
#pragma unroll
    for (int ks = 0; ks < 4; ++ks) {
        ahi_[ks] = *(const short8v*)(xhi + abase + ks * 16);
        alo_[ks] = *(const short8v*)(xlo + abase + ks * 16);
    }
    float sia_s[4][4];
#pragma unroll
    for (int q = 0; q < 4; ++q) {
        float4 t = *(const float4*)(sq + row0 + 8 * q + 4 * h);
        sia_s[q][0] = t.x * scale; sia_s[q][1] = t.y * scale;
        sia_s[q][2] = t.z * scale; sia_s[q][3] = t.w * scale;
    }
    __syncthreads();

    float bsr[4][4];
#pragma unroll
    for (int q = 0; q < 4; ++q) {
        float4 t = *(const float4*)(&bsf[8 * q + 4 * h]);
        bsr[q][0] = t.x; bsr[q][1] = t.y; bsr[q][2] = t.z; bsr[q][3] = t.w;
    }

    for (int s = 0; s < NSTEP; ++s) {
        const int gj = colbase + s * BCOL + wv * 32 + (lane & 31);
        const float sjs = sq[gj] * scale;
        f32x16 acc = dot_acc(xhi, xlo, ahi_, alo_, gj, h);
#pragma unroll
        for (int q = 0; q < 4; ++q)
#pragma unroll
            for (int j = 0; j < 4; ++j) {
                const int rl = 8 * q + 4 * h + j;
                const float binf = fmaf(ns, acc[4 * q + j], sia_s[q][j] + sjs);
                const bool pred = binf < bsr[q][j];   // == ((int)clamp(binf) <= B*)
                const unsigned long long mm = __ballot(pred);
                if (mm) {
                    const unsigned mh = (unsigned)(mm >> (h * 32));
                    int base = 0;
                    if ((lane & 31) == 0) base = atomicAdd(&gcnt[row0 + rl], __popc(mh));
                    base = __shfl(base, 0, 32);
                    if (pred) {
                        const int pos = base + __popc(mh & ((1u << (lane & 31)) - 1u));
                        if (pos < CAP) {
                            gbufv[(size_t)(row0 + rl) * CAP + pos] = binf * inv_scale;  // d2
                            gbufi[(size_t)(row0 + rl) * CAP + pos] = (unsigned short)gj;
                        }
                    }
                }
            }
    }
}

// -------- kernel D: exact top-90 select + beta bisection + Simpson ----------
__global__ __launch_bounds__(1024) void k_sel_lisi(const float* __restrict__ gbufv,
                                                   const unsigned short* __restrict__ gbufi,
                                                   const int* __restrict__ gcnt,
                                                   const int* __restrict__ batch,
                                                   float* __restrict__ out) {
    __shared__ float scrv[NWAVE][96];
    __shared__ unsigned short scri[NWAVE][96];

    const int lane = threadIdx.x & 63;
    const int w = threadIdx.x >> 6;
    const int row = blockIdx.x * NWAVE + w;
    const unsigned long long lt = (1ull << lane) - 1ull;

    int n = gcnt[row]; n = n < CAP ? n : CAP;
    const float* bv = gbufv + (size_t)row * CAP;
    const unsigned short* bi = gbufi + (size_t)row * CAP;

    float fv[QS]; unsigned short fi[QS]; unsigned uv[QS]; bool va[QS];
#pragma unroll
    for (int q = 0; q < QS; ++q) {
        int e = lane + 64 * q;
        bool inb = e < n;
        fv[q] = inb ? bv[e] : 0.f;
        fi[q] = inb ? bi[e] : (unsigned short)0;
        va[q] = inb && (fi[q] != (unsigned short)row);   // self filtered here
        uv[q] = __float_as_uint(fv[q]);
    }
    unsigned Tlo = 0u, Thi = 0x7F800000u;
    while (Thi - Tlo > 1u) {
        unsigned Tm = Tlo + ((Thi - Tlo) >> 1);
        int c = 0;
#pragma unroll
        for (int q = 0; q < QS; ++q)
            c += __popcll(__ballot(va[q] && uv[q] <= Tm));
        if (c >= NK) Thi = Tm; else Tlo = Tm;
    }
    int base = 0;
#pragma unroll
    for (int q = 0; q < QS; ++q) {
        bool p = va[q] && uv[q] < Thi;
        unsigned long long m = __ballot(p);
        if (p) { int pos = base + __popcll(m & lt); scrv[w][pos] = fv[q]; scri[w][pos] = fi[q]; }
        base += __popcll(m);
    }
    const int c1 = base;
    const int room = NK - c1;   // >= 0
    int tb = 0;
#pragma unroll
    for (int q = 0; q < QS; ++q) {
        bool p = va[q] && uv[q] == Thi;
        unsigned long long m = __ballot(p);
        if (p) {
            int o = tb + __popcll(m & lt);
            if (o < room) { scrv[w][c1 + o] = fv[q]; scri[w][c1 + o] = fi[q]; }
        }
        tb += __popcll(m);
    }
    // scratch is wave-private; within-wave LDS ordering handled by waitcnt

    const float logU = 3.4011974f;  // ln(30)
    const float d0 = sqrtf(fmaxf(scrv[w][lane], 0.f));
    const int i0 = scri[w][lane];
    const bool v1 = lane < (NK - 64);  // 26 extra lanes
    const float d1 = v1 ? sqrtf(fmaxf(scrv[w][64 + lane], 0.f)) : 0.f;
    const int i1 = v1 ? scri[w][64 + lane] : 0;
    const int l0 = batch[i0];
    const int l1 = v1 ? batch[i1] : -1;

    float beta = 1.f, bmin = -INFINITY, bmax = INFINITY;
    float P0, P1, S, H;

    auto hbeta = [&](float b) {
        P0 = __expf(-d0 * b);
        P1 = v1 ? __expf(-d1 * b) : 0.f;
        float s = P0 + P1;
        float ww = d0 * P0 + (v1 ? d1 * P1 : 0.f);
        for (int o = 32; o > 0; o >>= 1) {
            s += __shfl_xor(s, o, 64);
            ww += __shfl_xor(ww, o, 64);
        }
        S = s;
        H = (S > 0.f) ? (__logf(S) + b * ww / S) : 0.f;
    };

    hbeta(beta);
    float Hdiff = H - logU;
    for (int it = 0; it < 50; ++it) {
        if (fabsf(Hdiff) < 1e-5f) break;
        if (Hdiff > 0.f) {
            bmin = beta;
            beta = isinf(bmax) ? beta * 2.f : 0.5f * (beta + bmax);
        } else {
            bmax = beta;
            beta = isinf(bmin) ? beta * 0.5f : 0.5f * (beta + bmin);
        }
        hbeta(beta);
        Hdiff = H - logU;
    }

    const float Pn0 = (S > 0.f) ? P0 / S : 0.f;
    const float Pn1 = (S > 0.f && v1) ? P1 / S : 0.f;

    float simpson = 0.f;
#pragma unroll
    for (int c = 0; c < 8; ++c) {
        float v = (l0 == c ? Pn0 : 0.f) + (l1 == c ? Pn1 : 0.f);
        for (int o = 32; o > 0; o >>= 1) v += __shfl_xor(v, o, 64);
        simpson += v * v;
    }
    if (H == 0.f) simpson -= 1.f;
    if (lane == 0) out[row] = 1.f / simpson;
}

extern "C" void kernel_launch(void* const* d_in, const int* in_sizes, int n_in,
                              void* d_out, int out_size, void* d_ws, size_t ws_size,
                              hipStream_t stream) {
    const float* x = (const float*)d_in[0];
    const int* batch = (const int*)d_in[1];
    float* out = (float*)d_out;

    float* sq = (float*)d_ws;                              // [N] f32        32 KB
    int* maxbits = (int*)(sq + N);                         // [4]
    int* gcnt = maxbits + 4;                               // [N]            32 KB
    unsigned short* xhi = (unsigned short*)(gcnt + N);     // [N*D]           1 MB
    unsigned short* xlo = xhi + (size_t)N * D;             // [N*D]           1 MB
    unsigned short* ghist = xlo + (size_t)N * D;           // [512*32*256]    8 MB
    float* gbufv = (float*)(ghist + (size_t)2 * NBAND * BMR * NBIN);  // [N*CAP] 8 MB
    unsigned short* gbufi = (unsigned short*)(gbufv + (size_t)N * CAP);  // 4 MB

    k_prep<<<N / 256, 256, 0, stream>>>(x, xhi, xlo, sq, maxbits, gcnt);
    k_hist<<<2 * NBAND, 1024, 0, stream>>>(xhi, xlo, sq, maxbits, ghist);
    k_collect<<<2 * NBAND, 1024, 0, stream>>>(xhi, xlo, sq, maxbits, ghist, gcnt, gbufv, gbufi);
    k_sel_lisi<<<N / NWAVE, 1024, 0, stream>>>(gbufv, gbufi, gcnt, batch, out);
}

// Round 9
// 236.615 us; speedup vs baseline: 1.3825x; 1.3825x over previous
//
#include <hip/hip_runtime.h>
#include <math.h>
#include <float.h>

#define N 8192
#define D 64
#define NK 90               // neighbors kept (K+1=91 incl self; self excluded at select)
#define NK1 (NK + 1)        // per-half histogram target including potential self
#define BMR 32              // rows per band
#define NBAND (N / BMR)     // 256
#define HCOL (N / 2)        // 4096 cols per half-block
#define NWAVE 16
#define BCOL (NWAVE * 32)   // 512 cols per step
#define NSTEP (HCOL / BCOL) // 8
#define NBIN 256
#define CAP 192             // per-row per-half candidate capacity (LDS)
#define SQS 6               // (2*CAP)/64 for the merge-select

typedef __attribute__((ext_vector_type(8))) short short8v;
typedef __attribute__((ext_vector_type(16))) float f32x16;

__device__ __forceinline__ unsigned short f2bf(float f) {
    unsigned u = __float_as_uint(f);
    unsigned r = (u + 0x7FFFu + ((u >> 16) & 1u)) >> 16;   // RNE
    return (unsigned short)r;
}
__device__ __forceinline__ float bf2f(unsigned short h) {
    return __uint_as_float(((unsigned)h) << 16);
}

// ------------- kernel A: split-bf16 convert + row norms + global max --------
__global__ void k_prep(const float* __restrict__ x, unsigned short* __restrict__ xhi,
                       unsigned short* __restrict__ xlo, float* __restrict__ sq,
                       int* __restrict__ maxbits) {
    const int r = blockIdx.x * 256 + threadIdx.x;
    const float4* p = (const float4*)(x + (size_t)r * D);
    ushort4* ph = (ushort4*)(xhi + (size_t)r * D);
    ushort4* pl = (ushort4*)(xlo + (size_t)r * D);
    float s = 0.f;
#pragma unroll
    for (int q = 0; q < D / 4; ++q) {
        float4 v = p[q];
        s += v.x * v.x + v.y * v.y + v.z * v.z + v.w * v.w;
        ushort4 hh, ll;
        hh.x = f2bf(v.x); ll.x = f2bf(v.x - bf2f(hh.x));
        hh.y = f2bf(v.y); ll.y = f2bf(v.y - bf2f(hh.y));
        hh.z = f2bf(v.z); ll.z = f2bf(v.z - bf2f(hh.z));
        hh.w = f2bf(v.w); ll.w = f2bf(v.w - bf2f(hh.w));
        ph[q] = hh; pl[q] = ll;
    }
    sq[r] = s;
    // wave max then one atomic (positive floats: int-bit compare monotone;
    // poisoned 0xAAAAAAAA is negative as int, any positive wins)
    float m = s;
    for (int o = 32; o > 0; o >>= 1) m = fmaxf(m, __shfl_xor(m, o, 64));
    if ((threadIdx.x & 63) == 0) atomicMax(maxbits, __float_as_int(m));
}

// ---- shared MFMA dot core: bit-identical between phase 1 and phase 2 ----
__device__ __forceinline__ f32x16 dot_acc(const unsigned short* __restrict__ xhi,
                                          const unsigned short* __restrict__ xlo,
                                          const short8v* ahi, const short8v* alo,
                                          int gj, int h) {
    f32x16 acc;
#pragma unroll
    for (int i = 0; i < 16; ++i) acc[i] = 0.f;
    const unsigned short* bh = xhi + (size_t)gj * D + 8 * h;
    const unsigned short* bl = xlo + (size_t)gj * D + 8 * h;
#pragma unroll
    for (int ks = 0; ks < 4; ++ks) {
        short8v bhiv = *(const short8v*)(bh + ks * 16);
        short8v blov = *(const short8v*)(bl + ks * 16);
        acc = __builtin_amdgcn_mfma_f32_32x32x16_bf16(ahi[ks], bhiv, acc, 0, 0, 0);
        acc = __builtin_amdgcn_mfma_f32_32x32x16_bf16(ahi[ks], blov, acc, 0, 0, 0);
        acc = __builtin_amdgcn_mfma_f32_32x32x16_bf16(alo[ks], bhiv, acc, 0, 0, 0);
    }
    return acc;
}

// ---- kernel B: fused hist + local-B* + collect over a 32-row x 4096-col half
__global__ __launch_bounds__(1024) void k_knn2(const unsigned short* __restrict__ xhi,
                                               const unsigned short* __restrict__ xlo,
                                               const float* __restrict__ sq,
                                               const int* __restrict__ maxbits,
                                               float* __restrict__ gbufv,
                                               unsigned short* __restrict__ gbufi,
                                               int* __restrict__ gcnt) {
    __shared__ int hist[BMR][NBIN];              // 32 KB
    __shared__ float bufv[BMR][CAP];             // 24 KB
    __shared__ unsigned short bufi[BMR][CAP];    // 12 KB
    __shared__ int cnt[BMR];
    __shared__ float bsf[BMR];                   // float(B* + 1)

    const int tid = threadIdx.x;
    const int lane = tid & 63;
    const int h = lane >> 5;
    const int wv = tid >> 6;
    const int band = blockIdx.x >> 1;
    const int half = blockIdx.x & 1;
    const int colbase = half * HCOL;
    const int row0 = band * BMR;

    for (int e = tid; e < BMR * NBIN; e += 1024) ((int*)hist)[e] = 0;
    if (tid < BMR) cnt[tid] = 0;

    const float hi = 4.0f * __int_as_float(maxbits[0]) + 1.0f;   // > any d2
    const float scale = (float)NBIN / hi;
    const float inv_scale = hi / (float)NBIN;
    const float ns = -2.0f * scale;

    short8v ahi_[4], alo_[4];
    const size_t abase = (size_t)(row0 + (lane & 31)) * D + 8 * h;
#pragma unroll
    for (int ks = 0; ks < 4; ++ks) {
        ahi_[ks] = *(const short8v*)(xhi + abase + ks * 16);
        alo_[ks] = *(const short8v*)(xlo + abase + ks * 16);
    }
    float sia_s[4][4];
#pragma unroll
    for (int q = 0; q < 4; ++q) {
        float4 t = *(const float4*)(sq + row0 + 8 * q + 4 * h);
        sia_s[q][0] = t.x * scale; sia_s[q][1] = t.y * scale;
        sia_s[q][2] = t.z * scale; sia_s[q][3] = t.w * scale;
    }
    __syncthreads();

    // ---------- phase 1: histogram sweep (no barriers, no self-check) -------
    for (int s = 0; s < NSTEP; ++s) {
        const int gj = colbase + s * BCOL + wv * 32 + (lane & 31);
        const float sjs = sq[gj] * scale;
        f32x16 acc = dot_acc(xhi, xlo, ahi_, alo_, gj, h);
#pragma unroll
        for (int q = 0; q < 4; ++q)
#pragma unroll
            for (int j = 0; j < 4; ++j) {
                const float binf = fmaf(ns, acc[4 * q + j], sia_s[q][j] + sjs);
                const int bin = (int)fminf(fmaxf(binf, 0.f), (float)(NBIN - 1));
                atomicAdd(&hist[8 * q + 4 * h + j][bin], 1);
            }
    }
    __syncthreads();

    // ---------- local B* per row: cum >= NK1 within this half ----------
    // (union of per-half top-91 is a superset of the global top-91)
#pragma unroll 1
    for (int rr = 0; rr < 2; ++rr) {
        const int r = wv * 2 + rr;
        int pc[4]; int ssum = 0;
#pragma unroll
        for (int b = 0; b < 4; ++b) { pc[b] = hist[r][lane * 4 + b]; ssum += pc[b]; }
        int incl = ssum;
        for (int o = 1; o < 64; o <<= 1) {
            int t = __shfl_up(incl, o, 64);
            if (lane >= o) incl += t;
        }
        const int excl = incl - ssum;
        const bool has = (excl < NK1) && (incl >= NK1);
        const unsigned long long m = __ballot(has);
        const int src = __ffsll((unsigned long long)m) - 1;
        int bsel = NBIN - 1;
        if (has) {
            int c = excl;
#pragma unroll
            for (int b = 0; b < 4; ++b) {
                c += pc[b];
                if (c >= NK1) { bsel = lane * 4 + b; break; }
            }
        }
        bsel = __shfl(bsel, src, 64);
        if (lane == 0) bsf[r] = (float)(bsel + 1);
    }
    __syncthreads();

    float bsr[4][4];
#pragma unroll
    for (int q = 0; q < 4; ++q) {
        float4 t = *(const float4*)(&bsf[8 * q + 4 * h]);
        bsr[q][0] = t.x; bsr[q][1] = t.y; bsr[q][2] = t.z; bsr[q][3] = t.w;
    }

    // ---------- phase 2: collect sweep into LDS (identical arithmetic) ------
    for (int s = 0; s < NSTEP; ++s) {
        const int gj = colbase + s * BCOL + wv * 32 + (lane & 31);
        const float sjs = sq[gj] * scale;
        f32x16 acc = dot_acc(xhi, xlo, ahi_, alo_, gj, h);
#pragma unroll
        for (int q = 0; q < 4; ++q)
#pragma unroll
            for (int j = 0; j < 4; ++j) {
                const int rl = 8 * q + 4 * h + j;
                const float binf = fmaf(ns, acc[4 * q + j], sia_s[q][j] + sjs);
                const bool pred = binf < bsr[q][j];   // == ((int)clamp(binf) <= B*)
                const unsigned long long mm = __ballot(pred);
                if (mm) {
                    const unsigned mh = (unsigned)(mm >> (h * 32));
                    int base = 0;
                    if ((lane & 31) == 0) base = atomicAdd(&cnt[rl], __popc(mh));
                    base = __shfl(base, 0, 32);
                    if (pred) {
                        const int pos = base + __popc(mh & ((1u << (lane & 31)) - 1u));
                        if (pos < CAP) {
                            bufv[rl][pos] = binf * inv_scale;   // d2
                            bufi[rl][pos] = (unsigned short)gj;
                        }
                    }
                }
            }
    }
    __syncthreads();

    // ---------- coalesced dump: <=CAP candidates + count per row-half -------
    for (int e = tid; e < BMR * CAP; e += 1024) {
        const int r = e / CAP, k = e - r * CAP;
        const size_t dst = ((size_t)(row0 + r) * 2 + half) * CAP + k;
        gbufv[dst] = bufv[r][k];
        gbufi[dst] = bufi[r][k];
    }
    if (tid < BMR) {
        int n = cnt[tid];
        gcnt[(row0 + tid) * 2 + half] = n < CAP ? n : CAP;
    }
}

// -------- kernel C: merge halves, exact top-90, beta bisection + Simpson ----
__global__ __launch_bounds__(1024) void k_sel_lisi(const float* __restrict__ gbufv,
                                                   const unsigned short* __restrict__ gbufi,
                                                   const int* __restrict__ gcnt,
                                                   const int* __restrict__ batch,
                                                   float* __restrict__ out) {
    __shared__ float scrv[NWAVE][96];
    __shared__ unsigned short scri[NWAVE][96];

    const int lane = threadIdx.x & 63;
    const int w = threadIdx.x >> 6;
    const int row = blockIdx.x * NWAVE + w;
    const unsigned long long lt = (1ull << lane) - 1ull;

    const int n0 = gcnt[row * 2 + 0];
    const int n1 = gcnt[row * 2 + 1];
    const float* bv = gbufv + (size_t)row * 2 * CAP;
    const unsigned short* bi = gbufi + (size_t)row * 2 * CAP;

    float fv[SQS]; unsigned short fi[SQS]; unsigned uv[SQS]; bool va[SQS];
#pragma unroll
    for (int q = 0; q < SQS; ++q) {
        const int e = lane + 64 * q;            // 0..383
        const int hh = e >= CAP;
        const int k = e - hh * CAP;
        const bool inb = k < (hh ? n1 : n0);
        fv[q] = inb ? bv[e] : 0.f;
        fi[q] = inb ? bi[e] : (unsigned short)0;
        va[q] = inb && (fi[q] != (unsigned short)row);   // self filtered here
        uv[q] = __float_as_uint(fv[q]);
    }
    unsigned Tlo = 0u, Thi = 0x7F800000u;
    while (Thi - Tlo > 1u) {
        unsigned Tm = Tlo + ((Thi - Tlo) >> 1);
        int c = 0;
#pragma unroll
        for (int q = 0; q < SQS; ++q)
            c += __popcll(__ballot(va[q] && uv[q] <= Tm));
        if (c >= NK) Thi = Tm; else Tlo = Tm;
    }
    int base = 0;
#pragma unroll
    for (int q = 0; q < SQS; ++q) {
        bool p = va[q] && uv[q] < Thi;
        unsigned long long m = __ballot(p);
        if (p) { int pos = base + __popcll(m & lt); scrv[w][pos] = fv[q]; scri[w][pos] = fi[q]; }
        base += __popcll(m);
    }
    const int c1 = base;
    const int room = NK - c1;   // >= 0
    int tb = 0;
#pragma unroll
    for (int q = 0; q < SQS; ++q) {
        bool p = va[q] && uv[q] == Thi;
        unsigned long long m = __ballot(p);
        if (p) {
            int o = tb + __popcll(m & lt);
            if (o < room) { scrv[w][c1 + o] = fv[q]; scri[w][c1 + o] = fi[q]; }
        }
        tb += __popcll(m);
    }
    // scratch is wave-private; within-wave LDS ordering handled by waitcnt

    const float logU = 3.4011974f;  // ln(30)
    const float d0 = sqrtf(fmaxf(scrv[w][lane], 0.f));
    const int i0 = scri[w][lane];
    const bool v1 = lane < (NK - 64);  // 26 extra lanes
    const float d1 = v1 ? sqrtf(fmaxf(scrv[w][64 + lane], 0.f)) : 0.f;
    const int i1 = v1 ? scri[w][64 + lane] : 0;
    const int l0 = batch[i0];
    const int l1 = v1 ? batch[i1] : -1;

    float beta = 1.f, bmin = -INFINITY, bmax = INFINITY;
    float P0, P1, S, H;

    auto hbeta = [&](float b) {
        P0 = __expf(-d0 * b);
        P1 = v1 ? __expf(-d1 * b) : 0.f;
        float s = P0 + P1;
        float ww = d0 * P0 + (v1 ? d1 * P1 : 0.f);
        for (int o = 32; o > 0; o >>= 1) {
            s += __shfl_xor(s, o, 64);
            ww += __shfl_xor(ww, o, 64);
        }
        S = s;
        H = (S > 0.f) ? (__logf(S) + b * ww / S) : 0.f;
    };

    hbeta(beta);
    float Hdiff = H - logU;
    for (int it = 0; it < 50; ++it) {
        if (fabsf(Hdiff) < 1e-5f) break;
        if (Hdiff > 0.f) {
            bmin = beta;
            beta = isinf(bmax) ? beta * 2.f : 0.5f * (beta + bmax);
        } else {
            bmax = beta;
            beta = isinf(bmin) ? beta * 0.5f : 0.5f * (beta + bmin);
        }
        hbeta(beta);
        Hdiff = H - logU;
    }

    const float Pn0 = (S > 0.f) ? P0 / S : 0.f;
    const float Pn1 = (S > 0.f && v1) ? P1 / S : 0.f;

    float simpson = 0.f;
#pragma unroll
    for (int c = 0; c < 8; ++c) {
        float v = (l0 == c ? Pn0 : 0.f) + (l1 == c ? Pn1 : 0.f);
        for (int o = 32; o > 0; o >>= 1) v += __shfl_xor(v, o, 64);
        simpson += v * v;
    }
    if (H == 0.f) simpson -= 1.f;
    if (lane == 0) out[row] = 1.f / simpson;
}

extern "C" void kernel_launch(void* const* d_in, const int* in_sizes, int n_in,
                              void* d_out, int out_size, void* d_ws, size_t ws_size,
                              hipStream_t stream) {
    const float* x = (const float*)d_in[0];
    const int* batch = (const int*)d_in[1];
    float* out = (float*)d_out;

    float* sq = (float*)d_ws;                              // [N] f32       32 KB
    int* maxbits = (int*)(sq + N);                         // [4]
    int* gcnt = maxbits + 4;                               // [2N]          64 KB
    unsigned short* xhi = (unsigned short*)(gcnt + 2 * N); // [N*D]          1 MB
    unsigned short* xlo = xhi + (size_t)N * D;             // [N*D]          1 MB
    float* gbufv = (float*)(xlo + (size_t)N * D);          // [N*2*CAP]     12 MB
    unsigned short* gbufi = (unsigned short*)(gbufv + (size_t)N * 2 * CAP);  // 6 MB

    k_prep<<<N / 256, 256, 0, stream>>>(x, xhi, xlo, sq, maxbits);
    k_knn2<<<2 * NBAND, 1024, 0, stream>>>(xhi, xlo, sq, maxbits, gbufv, gbufi, gcnt);
    k_sel_lisi<<<N / NWAVE, 1024, 0, stream>>>(gbufv, gbufi, gcnt, batch, out);
}